// Round 15
// baseline (144.031 us; speedup 1.0000x reference)
//
#include <hip/hip_runtime.h>
#include <hip/hip_bf16.h>

#define SEQ 2048
#define EMB 128
#define KT 64
#define QT 64
#define NT 256
#define NITER (SEQ / KT)

typedef __attribute__((ext_vector_type(8))) short short8;
typedef __attribute__((ext_vector_type(4))) short sh4;
typedef __attribute__((ext_vector_type(4))) float floatx4;
typedef __attribute__((ext_vector_type(4))) unsigned short ushort4_t;

#if __has_builtin(__builtin_amdgcn_mfma_f32_16x16x16_bf16)
#define MFMA16(a, b, c) __builtin_amdgcn_mfma_f32_16x16x16_bf16(a, b, c, 0, 0, 0)
#elif __has_builtin(__builtin_amdgcn_mfma_f32_16x16x16bf16_1k)
#define MFMA16(a, b, c) __builtin_amdgcn_mfma_f32_16x16x16bf16_1k(a, b, c, 0, 0, 0)
#else
__device__ static inline floatx4 MFMA16(sh4, sh4, floatx4 c) { return c; }
#endif

__device__ __forceinline__ unsigned short f2bf(float x) {
  union { float f; unsigned u; } c; c.f = x;
  return (unsigned short)((c.u + 0x7fffu + ((c.u >> 16) & 1u)) >> 16);
}
// packed f32x2 -> bf16x2 via documented HIP API (RNE, == f2bf bitwise)
__device__ __forceinline__ unsigned packbf2(float a, float b) {
  union { __hip_bfloat162 h; unsigned u; } c;
  c.h = __float22bfloat162_rn(float2{a, b});
  return c.u;
}

// ---- fused pre-pass: K fp32->bf16 cvt  +  V fp32 -> Vt bf16 transpose ----
// (R3 original layout: G2 geometry reads natural columns, permutation reverted)
__global__ void prep_kernel(const float* __restrict__ K, unsigned short* __restrict__ Kb,
                            const float* __restrict__ V, unsigned short* __restrict__ Vtb,
                            int nblkK) {
  const int tid = threadIdx.x;
  if ((int)blockIdx.x < nblkK) {
    int i = blockIdx.x * NT + tid;
    float4 v = ((const float4*)K)[i];
    ((ushort4_t*)Kb)[i] = (ushort4_t){f2bf(v.x), f2bf(v.y), f2bf(v.z), f2bf(v.w)};
    return;
  }
  const int rb = blockIdx.x - nblkK;
  const int s0 = (rb & 31) * 64;
  const int e0 = ((rb >> 5) & 1) * 64;
  const int b  = rb >> 6;
  const float* src = V + (size_t)b * SEQ * EMB;
  unsigned short* dst = Vtb + (size_t)b * EMB * SEQ;
  const int k = (tid & 15) * 4;
  const int e = (tid >> 4) * 4;
  const float* vb = src + (size_t)(s0 + k) * EMB + e0 + e;
  float4 r0 = *(const float4*)(vb);
  float4 r1 = *(const float4*)(vb + EMB);
  float4 r2 = *(const float4*)(vb + 2 * EMB);
  float4 r3 = *(const float4*)(vb + 3 * EMB);
  unsigned short* d0 = dst + (size_t)(e0 + e) * SEQ + s0 + k;
  *(ushort4_t*)(d0)           = (ushort4_t){f2bf(r0.x), f2bf(r1.x), f2bf(r2.x), f2bf(r3.x)};
  *(ushort4_t*)(d0 + SEQ)     = (ushort4_t){f2bf(r0.y), f2bf(r1.y), f2bf(r2.y), f2bf(r3.y)};
  *(ushort4_t*)(d0 + 2 * SEQ) = (ushort4_t){f2bf(r0.z), f2bf(r1.z), f2bf(r2.z), f2bf(r3.z)};
  *(ushort4_t*)(d0 + 3 * SEQ) = (ushort4_t){f2bf(r0.w), f2bf(r1.w), f2bf(r2.w), f2bf(r3.w)};
}

// ---- main kernel G2: 4 waves, k-split 4-way (16 cols/wave), each wave owns
//      ALL 64 q-rows -> every staged LDS byte read exactly once (was 2x).
//      In-tile PV (no cross-tile reg state). V-frags = b64 reads, ~2-way
//      conflicts (free). Epilogue: sequential 4-wave slab reduce.
//      Keeps: packbf2, XCD swizzle, no setprio, global_load_lds staging. ----
__global__ __launch_bounds__(NT, 2)
void fattn7(const float* __restrict__ Qp, const unsigned short* __restrict__ Kb,
            const unsigned short* __restrict__ Vtb, float* __restrict__ Op) {
  __shared__ __align__(16) unsigned char smem[65536];
  unsigned short* Ks = (unsigned short*)smem;            // [2][KT][EMB] 32 KB
  unsigned short* Vs = Ks + 2 * KT * EMB;                // [2][EMB][KT] 32 KB
  float* slab  = (float*)smem;                           // [64][132] epilogue alias
  float* lredA = (float*)(smem + 64 * 132 * 4);          // [4][64]

  const int tid  = threadIdx.x;
  const int lane = tid & 63;
  const int w    = tid >> 6;     // 0..3 = wk (k-quarter, 16 cols)
  const int n16  = lane & 15, quad = lane >> 4;
  const int wk   = w;
  // XCD-aware bijective swizzle (nwg % 8 == 0: nwg = 32*B)
  const int bid = blockIdx.x;
  const int cpx = (int)(gridDim.x >> 3);
  const int wg  = (bid & 7) * cpx + (bid >> 3);
  const int b   = wg >> 5, q0 = (wg & 31) * QT;
  const size_t bo = (size_t)b * SEQ * EMB;

  auto* ks3 = (__attribute__((address_space(3))) unsigned short*)Ks;
  auto* vs3 = (__attribute__((address_space(3))) unsigned short*)Vs;

  const int krw = tid >> 4, kgs = tid & 15;
  const int vrw = tid >> 3, vgs = tid & 7;
  const unsigned short* pK = Kb + bo + (size_t)krw * EMB + (size_t)((kgs ^ (krw & 7)) * 8);
  const unsigned short* pV = Vtb + bo + (size_t)vrw * SEQ + (size_t)((vgs ^ (vrw & 7)) * 8);

  // Q frags: all 64 q-rows per wave (4 nt)
  short8 qf[4][4];
#pragma unroll
  for (int nt = 0; nt < 4; ++nt) {
    const float* qr = Qp + bo + (size_t)(q0 + nt * 16 + n16) * EMB + quad * 8;
#pragma unroll
    for (int e = 0; e < 4; ++e) {
      float4 x = *(const float4*)(qr + e * 32);
      float4 y = *(const float4*)(qr + e * 32 + 4);
      qf[nt][e] = (short8){(short)f2bf(x.x), (short)f2bf(x.y), (short)f2bf(x.z), (short)f2bf(x.w),
                           (short)f2bf(y.x), (short)f2bf(y.y), (short)f2bf(y.z), (short)f2bf(y.w)};
    }
  }

  int koff[4];
#pragma unroll
  for (int e = 0; e < 4; ++e) koff[e] = ((e * 4 + quad) ^ (n16 & 7)) * 8;
  // V b64 read: global k = wk*16 + quad*4 (+i) of row t*16+n16.
  // 16B-chunk g = 2*wk + (quad>>1), XOR staging swizzle by row&7 = n16&7,
  // sub-half (quad&1)*4 shorts.  (short units; + t*1024 per t)
  const int voffs = n16 * KT + ((2 * wk + (quad >> 1)) ^ (n16 & 7)) * 8 + (quad & 1) * 4;

  floatx4 o[8][4];
#pragma unroll
  for (int t = 0; t < 8; ++t)
#pragma unroll
    for (int nt = 0; nt < 4; ++nt) o[t][nt] = (floatx4){0.f, 0.f, 0.f, 0.f};
  float lp[4] = {0.f, 0.f, 0.f, 0.f};

  const float SCALE = 0.08838834764831845f;
  const float L2E = 1.4426950408889634f;
  const float C1 = SCALE * L2E;

  auto issue = [&](int buf) {
    auto* kb = ks3 + buf * (KT * EMB) + w * 512;
    auto* vb = vs3 + buf * (EMB * KT) + w * 512;
    const unsigned short* gv = pV;
#pragma unroll
    for (int j = 0; j < 4; ++j) {
      __builtin_amdgcn_global_load_lds((const __attribute__((address_space(1))) void*)pK,
                                       (__attribute__((address_space(3))) void*)(kb + j * 2048), 16, 0, 0);
      pK += 2048;
      __builtin_amdgcn_global_load_lds((const __attribute__((address_space(1))) void*)gv,
                                       (__attribute__((address_space(3))) void*)(vb + j * 2048), 16, 0, 0);
      gv += 32 * SEQ;
    }
    pV += KT;
  };

  issue(0);

  for (int it = 0; it < NITER; ++it) {
    const int cur = it & 1;
    __syncthreads();
    if (it + 1 < NITER) issue(cur ^ 1);

    const unsigned short* kbase = Ks + cur * (KT * EMB);
    const unsigned short* vbase = Vs + cur * (EMB * KT);

    // V-frag b64 reads issued early (latency hides under QK^T)
    sh4 vfrag[8];
#pragma unroll
    for (int t = 0; t < 8; ++t)
      vfrag[t] = *(const sh4*)(vbase + t * 1024 + voffs);

    // ---- S^T = K Q^T (16 k-cols x 64 q-rows) ----
    floatx4 s[4];
#pragma unroll
    for (int nt = 0; nt < 4; ++nt) s[nt] = (floatx4){0.f, 0.f, 0.f, 0.f};
#pragma unroll
    for (int e = 0; e < 4; ++e) {
      short8 ak = *(const short8*)(kbase + (wk * 16 + n16) * EMB + koff[e]);
#pragma unroll
      for (int nt = 0; nt < 4; ++nt)
        s[nt] = __builtin_amdgcn_mfma_f32_16x16x32_bf16(ak, qf[nt][e], s[nt], 0, 0, 0);
    }

    // ---- softmax (unnormalized) + pack to PV B-frags ----
    sh4 pb[4];
#pragma unroll
    for (int nt = 0; nt < 4; ++nt) {
      float p0 = __builtin_amdgcn_exp2f(s[nt][0] * C1);
      float p1 = __builtin_amdgcn_exp2f(s[nt][1] * C1);
      float p2 = __builtin_amdgcn_exp2f(s[nt][2] * C1);
      float p3 = __builtin_amdgcn_exp2f(s[nt][3] * C1);
      lp[nt] += (p0 + p1) + (p2 + p3);
      union { unsigned u[2]; sh4 v; } cc;
      cc.u[0] = packbf2(p0, p1);
      cc.u[1] = packbf2(p2, p3);
      pb[nt] = cc.v;
    }

    // ---- PV (in-tile) ----
#pragma unroll
    for (int t = 0; t < 8; ++t)
#pragma unroll
      for (int nt = 0; nt < 4; ++nt)
        o[t][nt] = MFMA16(vfrag[t], pb[nt], o[t][nt]);
  }

  // ---- lp: reduce over wave's 16 k (quad groups) ----
#pragma unroll
  for (int nt = 0; nt < 4; ++nt) {
    lp[nt] += __shfl_xor(lp[nt], 16);
    lp[nt] += __shfl_xor(lp[nt], 32);
  }

  // ---- epilogue: sequential slab reduce across 4 k-slices (waves 3->0) ----
  __syncthreads();
  if (w == 3) {
#pragma unroll
    for (int t = 0; t < 8; ++t)
#pragma unroll
      for (int nt = 0; nt < 4; ++nt)
        *(floatx4*)&slab[(nt * 16 + n16) * 132 + t * 16 + quad * 4] = o[t][nt];
    if (quad == 0)
#pragma unroll
      for (int nt = 0; nt < 4; ++nt) lredA[3 * 64 + nt * 16 + n16] = lp[nt];
  }
  __syncthreads();
  if (w == 2) {
#pragma unroll
    for (int t = 0; t < 8; ++t)
#pragma unroll
      for (int nt = 0; nt < 4; ++nt) {
        float* p = &slab[(nt * 16 + n16) * 132 + t * 16 + quad * 4];
        floatx4 r = *(const floatx4*)p;
        r[0] += o[t][nt][0]; r[1] += o[t][nt][1]; r[2] += o[t][nt][2]; r[3] += o[t][nt][3];
        *(floatx4*)p = r;
      }
    if (quad == 0)
#pragma unroll
      for (int nt = 0; nt < 4; ++nt) lredA[2 * 64 + nt * 16 + n16] = lp[nt];
  }
  __syncthreads();
  if (w == 1) {
#pragma unroll
    for (int t = 0; t < 8; ++t)
#pragma unroll
      for (int nt = 0; nt < 4; ++nt) {
        float* p = &slab[(nt * 16 + n16) * 132 + t * 16 + quad * 4];
        floatx4 r = *(const floatx4*)p;
        r[0] += o[t][nt][0]; r[1] += o[t][nt][1]; r[2] += o[t][nt][2]; r[3] += o[t][nt][3];
        *(floatx4*)p = r;
      }
    if (quad == 0)
#pragma unroll
      for (int nt = 0; nt < 4; ++nt) lredA[1 * 64 + nt * 16 + n16] = lp[nt];
  }
  __syncthreads();
  if (w == 0) {
    float inv[4];
#pragma unroll
    for (int nt = 0; nt < 4; ++nt) {
      const int r = nt * 16 + n16;
      inv[nt] = 1.0f / (lp[nt] + lredA[64 + r] + lredA[128 + r] + lredA[192 + r]);
    }
#pragma unroll
    for (int t = 0; t < 8; ++t)
#pragma unroll
      for (int nt = 0; nt < 4; ++nt) {
        floatx4 r = *(const floatx4*)&slab[(nt * 16 + n16) * 132 + t * 16 + quad * 4];
        const int q = q0 + nt * 16 + n16;
        float4 st = {(o[t][nt][0] + r[0]) * inv[nt], (o[t][nt][1] + r[1]) * inv[nt],
                     (o[t][nt][2] + r[2]) * inv[nt], (o[t][nt][3] + r[3]) * inv[nt]};
        *(float4*)(Op + bo + (size_t)q * EMB + t * 16 + quad * 4) = st;
      }
  }
}

extern "C" void kernel_launch(void* const* d_in, const int* in_sizes, int n_in,
                              void* d_out, int out_size, void* d_ws, size_t ws_size,
                              hipStream_t stream) {
  const float* Q = (const float*)d_in[0];
  const float* K = (const float*)d_in[1];
  const float* V = (const float*)d_in[2];
  float* O = (float*)d_out;
  const int B = in_sizes[0] / (SEQ * EMB);
  const size_t tsz = (size_t)B * SEQ * EMB;

  unsigned short* Kb = (unsigned short*)d_ws;
  unsigned short* Vtb = Kb + tsz;

  const int nblkK = (int)(tsz / 4 / NT);
  const int nblkV = (SEQ / 64) * (EMB / 64) * B;
  prep_kernel<<<nblkK + nblkV, NT, 0, stream>>>(K, Kb, V, Vtb, nblkK);
  fattn7<<<dim3((SEQ / QT) * B), NT, 0, stream>>>(Q, Kb, Vtb, O);
}

// Round 17
// 132.448 us; speedup vs baseline: 1.0874x; 1.0874x over previous
//
#include <hip/hip_runtime.h>
#include <hip/hip_bf16.h>

#define SEQ 2048
#define EMB 128
#define KT 64
#define QT 64
#define NT 256
#define NITER (SEQ / KT)

typedef __attribute__((ext_vector_type(8))) short short8;
typedef __attribute__((ext_vector_type(4))) short sh4;
typedef __attribute__((ext_vector_type(4))) float floatx4;
typedef __attribute__((ext_vector_type(4))) unsigned short ushort4_t;

__device__ __forceinline__ unsigned short f2bf(float x) {
  union { float f; unsigned u; } c; c.f = x;
  return (unsigned short)((c.u + 0x7fffu + ((c.u >> 16) & 1u)) >> 16);
}
// packed f32x2 -> bf16x2 via documented HIP API (RNE, == f2bf bitwise)
__device__ __forceinline__ unsigned packbf2(float a, float b) {
  union { __hip_bfloat162 h; unsigned u; } c;
  c.h = __float22bfloat162_rn(float2{a, b});
  return c.u;
}

// ---- fused pre-pass: K fp32->bf16 cvt  +  V fp32 -> Vt bf16 transpose ----
// (R12 WIN: V columns permuted within each 64-tile, col' = g*32+quad*8+mt*4+j)
__global__ void prep_kernel(const float* __restrict__ K, unsigned short* __restrict__ Kb,
                            const float* __restrict__ V, unsigned short* __restrict__ Vtb,
                            int nblkK) {
  const int tid = threadIdx.x;
  if ((int)blockIdx.x < nblkK) {
    int i = blockIdx.x * NT + tid;
    float4 v = ((const float4*)K)[i];
    ((ushort4_t*)Kb)[i] = (ushort4_t){f2bf(v.x), f2bf(v.y), f2bf(v.z), f2bf(v.w)};
    return;
  }
  const int rb = blockIdx.x - nblkK;
  const int s0 = (rb & 31) * 64;
  const int e0 = ((rb >> 5) & 1) * 64;
  const int b  = rb >> 6;
  const float* src = V + (size_t)b * SEQ * EMB;
  unsigned short* dst = Vtb + (size_t)b * EMB * SEQ;
  const int k = (tid & 15) * 4;
  const int e = (tid >> 4) * 4;
  const int kp = (k & 32) + (((k >> 2) & 3) * 8) + (((k >> 4) & 1) * 4);
  const float* vb = src + (size_t)(s0 + k) * EMB + e0 + e;
  float4 r0 = *(const float4*)(vb);
  float4 r1 = *(const float4*)(vb + EMB);
  float4 r2 = *(const float4*)(vb + 2 * EMB);
  float4 r3 = *(const float4*)(vb + 3 * EMB);
  unsigned short* d0 = dst + (size_t)(e0 + e) * SEQ + s0 + kp;
  *(ushort4_t*)(d0)           = (ushort4_t){f2bf(r0.x), f2bf(r1.x), f2bf(r2.x), f2bf(r3.x)};
  *(ushort4_t*)(d0 + SEQ)     = (ushort4_t){f2bf(r0.y), f2bf(r1.y), f2bf(r2.y), f2bf(r3.y)};
  *(ushort4_t*)(d0 + 2 * SEQ) = (ushort4_t){f2bf(r0.z), f2bf(r1.z), f2bf(r2.z), f2bf(r3.z)};
  *(ushort4_t*)(d0 + 3 * SEQ) = (ushort4_t){f2bf(r0.w), f2bf(r1.w), f2bf(r2.w), f2bf(r3.w)};
}

// ---- main kernel: R14 WIN structure (4 waves 2x2, V staged + b128 pulls,
//      static 2x-unroll, ping-pong regs, packbf2, XCD swizzle, no setprio).
//      THIS ROUND'S ONLY DELTA: PV uses mfma 16x16x32 (K=32) — the prep
//      permutation puts A and B sides under the SAME k-permutation, so one
//      MFMA32 replaces two MFMA16 per (t,nt): 32 -> 16 PV MFMAs/tile/wave. ----
__global__ __launch_bounds__(NT, 2)
void fattn7(const float* __restrict__ Qp, const unsigned short* __restrict__ Kb,
            const unsigned short* __restrict__ Vtb, float* __restrict__ Op) {
  __shared__ __align__(16) unsigned char smem[65536];
  unsigned short* Ks = (unsigned short*)smem;            // [2][KT][EMB] 32 KB
  unsigned short* Vs = Ks + 2 * KT * EMB;                // [2][EMB][KT] 32 KB
  float* Ored = (float*)smem;                            // [2][32][132] (epilogue alias)
  float* lred = (float*)(smem + 2 * 32 * 132 * 4);       // [2][32]

  const int tid  = threadIdx.x;
  const int lane = tid & 63;
  const int w    = tid >> 6;
  const int n16  = lane & 15, quad = lane >> 4;
  const int wq   = w & 1;
  const int wk   = w >> 1;
  // XCD-aware bijective swizzle (nwg % 8 == 0: nwg = 32*B)
  const int bid = blockIdx.x;
  const int cpx = (int)(gridDim.x >> 3);
  const int wg  = (bid & 7) * cpx + (bid >> 3);
  const int b   = wg >> 5, q0 = (wg & 31) * QT;
  const size_t bo = (size_t)b * SEQ * EMB;

  auto* ks3 = (__attribute__((address_space(3))) unsigned short*)Ks;
  auto* vs3 = (__attribute__((address_space(3))) unsigned short*)Vs;

  const int krw = tid >> 4, kgs = tid & 15;
  const int vrw = tid >> 3, vgs = tid & 7;
  const unsigned short* pK = Kb + bo + (size_t)krw * EMB + (size_t)((kgs ^ (krw & 7)) * 8);
  const unsigned short* pV = Vtb + bo + (size_t)vrw * SEQ + (size_t)((vgs ^ (vrw & 7)) * 8);

  short8 qf[2][4];
#pragma unroll
  for (int nt = 0; nt < 2; ++nt) {
    const float* qr = Qp + bo + (size_t)(q0 + wq * 32 + nt * 16 + n16) * EMB + quad * 8;
#pragma unroll
    for (int e = 0; e < 4; ++e) {
      float4 x = *(const float4*)(qr + e * 32);
      float4 y = *(const float4*)(qr + e * 32 + 4);
      qf[nt][e] = (short8){(short)f2bf(x.x), (short)f2bf(x.y), (short)f2bf(x.z), (short)f2bf(x.w),
                           (short)f2bf(y.x), (short)f2bf(y.y), (short)f2bf(y.z), (short)f2bf(y.w)};
    }
  }

  int koff[4];
#pragma unroll
  for (int e = 0; e < 4; ++e) koff[e] = ((e * 4 + quad) ^ (n16 & 7)) * 8;
  // V b128 read: global 16B-chunk (wk*4+quad) of row t*16+n16, XOR staging swizzle
  const int voff = ((wk * 4 + quad) ^ (n16 & 7)) * 8;

  floatx4 o[8][2];
#pragma unroll
  for (int t = 0; t < 8; ++t)
#pragma unroll
    for (int nt = 0; nt < 2; ++nt) o[t][nt] = (floatx4){0.f, 0.f, 0.f, 0.f};
  float lp[2] = {0.f, 0.f};

  const float SCALE = 0.08838834764831845f;
  const float L2E = 1.4426950408889634f;
  const float C1 = SCALE * L2E;

  auto issue = [&](int buf) {
    auto* kb = ks3 + buf * (KT * EMB) + w * 512;
    auto* vb = vs3 + buf * (EMB * KT) + w * 512;
    const unsigned short* gv = pV;
#pragma unroll
    for (int j = 0; j < 4; ++j) {
      __builtin_amdgcn_global_load_lds((const __attribute__((address_space(1))) void*)pK,
                                       (__attribute__((address_space(3))) void*)(kb + j * 2048), 16, 0, 0);
      pK += 2048;
      __builtin_amdgcn_global_load_lds((const __attribute__((address_space(1))) void*)gv,
                                       (__attribute__((address_space(3))) void*)(vb + j * 2048), 16, 0, 0);
      gv += 32 * SEQ;
    }
    pV += KT;
  };

  issue(0);

  // named ping-pong state: B-slots are "prev" for tile 0.
  // pst8: per nt, 4 dwords = [mt0 p0p1, mt0 p2p3, mt1 p0p1, mt1 p2p3]
  short8 vstA[8], vstB[8];
  unsigned pstA[2][4], pstB[2][4];
#pragma unroll
  for (int t = 0; t < 8; ++t) vstB[t] = (short8){0, 0, 0, 0, 0, 0, 0, 0};
#pragma unroll
  for (int nt = 0; nt < 2; ++nt) {
    pstB[nt][0] = 0; pstB[nt][1] = 0; pstB[nt][2] = 0; pstB[nt][3] = 0;
  }

#define FA_BODY(CUR, VC, VP, PC, PP)                                                     \
  {                                                                                      \
    floatx4 s[2][2];                                                                     \
    _Pragma("unroll") for (int mt = 0; mt < 2; ++mt)                                     \
      _Pragma("unroll") for (int nt = 0; nt < 2; ++nt)                                   \
        s[mt][nt] = (floatx4){0.f, 0.f, 0.f, 0.f};                                       \
    const unsigned short* kbase = Ks + (CUR) * (KT * EMB);                               \
    _Pragma("unroll") for (int e = 0; e < 4; ++e) {                                      \
      _Pragma("unroll") for (int mt = 0; mt < 2; ++mt) {                                 \
        short8 ak = *(const short8*)(kbase + (wk * 32 + mt * 16 + n16) * EMB + koff[e]); \
        s[mt][0] = __builtin_amdgcn_mfma_f32_16x16x32_bf16(ak, qf[0][e], s[mt][0], 0, 0, 0); \
        s[mt][1] = __builtin_amdgcn_mfma_f32_16x16x32_bf16(ak, qf[1][e], s[mt][1], 0, 0, 0); \
      }                                                                                  \
    }                                                                                    \
    const unsigned short* vbase = Vs + (CUR) * (EMB * KT);                               \
    _Pragma("unroll") for (int t = 0; t < 8; ++t)                                        \
      VC[t] = *(const short8*)(vbase + (t * 16 + n16) * KT + voff);                      \
    short8 pb[2];                                                                        \
    _Pragma("unroll") for (int nt = 0; nt < 2; ++nt) {                                   \
      union { unsigned u[4]; short8 v; } cc;                                             \
      cc.u[0] = PP[nt][0]; cc.u[1] = PP[nt][1];                                          \
      cc.u[2] = PP[nt][2]; cc.u[3] = PP[nt][3];                                          \
      pb[nt] = cc.v;                                                                     \
    }                                                                                    \
    _Pragma("unroll") for (int t = 0; t < 8; ++t) {                                      \
      o[t][0] = __builtin_amdgcn_mfma_f32_16x16x32_bf16(VP[t], pb[0], o[t][0], 0, 0, 0); \
      o[t][1] = __builtin_amdgcn_mfma_f32_16x16x32_bf16(VP[t], pb[1], o[t][1], 0, 0, 0); \
    }                                                                                    \
    _Pragma("unroll") for (int mt = 0; mt < 2; ++mt)                                     \
      _Pragma("unroll") for (int nt = 0; nt < 2; ++nt) {                                 \
        float p0 = __builtin_amdgcn_exp2f(s[mt][nt][0] * C1);                            \
        float p1 = __builtin_amdgcn_exp2f(s[mt][nt][1] * C1);                            \
        float p2 = __builtin_amdgcn_exp2f(s[mt][nt][2] * C1);                            \
        float p3 = __builtin_amdgcn_exp2f(s[mt][nt][3] * C1);                            \
        lp[nt] += (p0 + p1) + (p2 + p3);                                                 \
        PC[nt][mt * 2 + 0] = packbf2(p0, p1);                                            \
        PC[nt][mt * 2 + 1] = packbf2(p2, p3);                                            \
      }                                                                                  \
  }

  for (int it2 = 0; it2 < NITER / 2; ++it2) {
    __syncthreads();
    issue(1);
    FA_BODY(0, vstA, vstB, pstA, pstB)
    __syncthreads();
    if (it2 + 1 < NITER / 2) issue(0);
    FA_BODY(1, vstB, vstA, pstB, pstA)
  }

  // ---- trailing PV for the last tile (B-slots) ----
  {
    short8 pb[2];
#pragma unroll
    for (int nt = 0; nt < 2; ++nt) {
      union { unsigned u[4]; short8 v; } cc;
      cc.u[0] = pstB[nt][0]; cc.u[1] = pstB[nt][1];
      cc.u[2] = pstB[nt][2]; cc.u[3] = pstB[nt][3];
      pb[nt] = cc.v;
    }
#pragma unroll
    for (int t = 0; t < 8; ++t) {
      o[t][0] = __builtin_amdgcn_mfma_f32_16x16x32_bf16(vstB[t], pb[0], o[t][0], 0, 0, 0);
      o[t][1] = __builtin_amdgcn_mfma_f32_16x16x32_bf16(vstB[t], pb[1], o[t][1], 0, 0, 0);
    }
  }

  // ---- epilogue: reduce across k-halves via LDS (aliased over staging) ----
#pragma unroll
  for (int nt = 0; nt < 2; ++nt) {
    lp[nt] += __shfl_xor(lp[nt], 16);
    lp[nt] += __shfl_xor(lp[nt], 32);
  }
  __syncthreads();
  if (wk) {
#pragma unroll
    for (int t = 0; t < 8; ++t)
#pragma unroll
      for (int nt = 0; nt < 2; ++nt)
        *(floatx4*)&Ored[((wq * 32) + nt * 16 + n16) * 132 + t * 16 + quad * 4] = o[t][nt];
    if (quad == 0) {
      lred[wq * 32 + n16] = lp[0];
      lred[wq * 32 + 16 + n16] = lp[1];
    }
  }
  __syncthreads();
  if (!wk) {
    float inv[2];
#pragma unroll
    for (int nt = 0; nt < 2; ++nt)
      inv[nt] = 1.0f / (lp[nt] + lred[wq * 32 + nt * 16 + n16]);
#pragma unroll
    for (int t = 0; t < 8; ++t)
#pragma unroll
      for (int nt = 0; nt < 2; ++nt) {
        floatx4 r = *(const floatx4*)&Ored[((wq * 32) + nt * 16 + n16) * 132 + t * 16 + quad * 4];
        const int q = q0 + wq * 32 + nt * 16 + n16;
        float4 st = {(o[t][nt][0] + r[0]) * inv[nt], (o[t][nt][1] + r[1]) * inv[nt],
                     (o[t][nt][2] + r[2]) * inv[nt], (o[t][nt][3] + r[3]) * inv[nt]};
        *(float4*)(Op + bo + (size_t)q * EMB + t * 16 + quad * 4) = st;
      }
  }
}

extern "C" void kernel_launch(void* const* d_in, const int* in_sizes, int n_in,
                              void* d_out, int out_size, void* d_ws, size_t ws_size,
                              hipStream_t stream) {
  const float* Q = (const float*)d_in[0];
  const float* K = (const float*)d_in[1];
  const float* V = (const float*)d_in[2];
  float* O = (float*)d_out;
  const int B = in_sizes[0] / (SEQ * EMB);
  const size_t tsz = (size_t)B * SEQ * EMB;

  unsigned short* Kb = (unsigned short*)d_ws;
  unsigned short* Vtb = Kb + tsz;

  const int nblkK = (int)(tsz / 4 / NT);
  const int nblkV = (SEQ / 64) * (EMB / 64) * B;
  prep_kernel<<<nblkK + nblkV, NT, 0, stream>>>(K, Kb, V, Vtb, nblkK);
  fattn7<<<dim3((SEQ / QT) * B), NT, 0, stream>>>(Q, Kb, Vtb, O);
}